// Round 5
// baseline (244.099 us; speedup 1.0000x reference)
//
#include <hip/hip_runtime.h>
#include <math.h>

#define NN   10000
#define DEG  16
#define SS   128
#define NRBF 20
#define GG   64
#define RC   10.0f
#define PI_F 3.14159265897932f
#define NBK  16          // nodes per k_update block
#define PAD  20          // LDS row stride (floats): 80B, 16B-aligned

__device__ __forceinline__ float silu_f(float x){
    return x / (1.0f + __expf(-x));
}

// ---------------------------------------------------------------------------
// Kernel 1: phi (uniform across edges at round 0) — fused h + phiW slice.
// 12 blocks; each block redundantly computes h, then 32 phiW channels.
// Also zeroes the graph accumulator gs.
// ---------------------------------------------------------------------------
__global__ __launch_bounds__(128) void k_phi(
    const float* __restrict__ emb0,
    const float* __restrict__ w1, const float* __restrict__ b1,
    const float* __restrict__ w2, const float* __restrict__ b2,
    float* __restrict__ phiW, float* __restrict__ gs){
    __shared__ float s0[SS];
    __shared__ float hL[SS];
    __shared__ float part[4][32];
    int t = threadIdx.x;
    for (int i = blockIdx.x*128 + t; i < GG*SS; i += 12*128) gs[i] = 0.0f;
    s0[t] = 128.0f * emb0[t];
    __syncthreads();
    float acc = b1[t];
    #pragma unroll 4
    for (int s = 0; s < SS; s++) acc = fmaf(s0[s], w1[s*SS + t], acc);
    hL[t] = silu_f(acc);
    __syncthreads();
    int c  = blockIdx.x*32 + (t & 31);
    int kk = t >> 5;
    float a = 0.0f;
    int sbase = kk * 32;
    #pragma unroll 8
    for (int s = 0; s < 32; s++)
        a = fmaf(hL[sbase + s], w2[(sbase + s)*3*SS + c], a);
    part[kk][t & 31] = a;
    __syncthreads();
    if (t < 32){
        int cc = blockIdx.x*32 + t;
        phiW[cc] = b2[cc] + part[0][t] + part[1][t] + part[2][t] + part[3][t];
    }
}

// ---------------------------------------------------------------------------
// Kernel 2: per-node edge processing, 64 threads/block (ONE wave).
// Thread t computes 4 channels: m2 {128+t, 192+t} -> state,
// m3 {256+t, 320+t} -> sv.  (round-4 version, kept)
// ---------------------------------------------------------------------------
__global__ __launch_bounds__(64) void k_edge(
    const float* __restrict__ evd, const float* __restrict__ elen,
    const int* __restrict__ node_from,
    const float* __restrict__ filt_w, const float* __restrict__ filt_b,
    const float* __restrict__ phiW,
    float* __restrict__ state, float* __restrict__ sv){
    __shared__ float rS[DEG];
    __shared__ float mcL[DEG];
    __shared__ float frL[DEG];
    __shared__ float eV[DEG][3];
    __shared__ float rbfL[DEG][NRBF];
    __shared__ float invD;
    int n = blockIdx.x;
    int t = threadIdx.x;

    if (t < DEG){
        int e = n*DEG + t;
        float x = evd[3*e+0], y = evd[3*e+1], z = evd[3*e+2];
        float r = sqrtf(x*x + y*y + z*z);
        float len  = elen[e];
        float mask = (fabsf(len) <= RC) ? 1.0f : 0.0f;
        float cut  = (r < RC) ? 0.5f*(cosf(PI_F*r*(1.0f/RC)) + 1.0f) : 0.0f;
        rS[t]  = fmaxf(r, 1e-12f);
        mcL[t] = mask * cut;
        frL[t] = mask * r * r;
        eV[t][0] = x; eV[t][1] = y; eV[t][2] = z;
    }
    __syncthreads();
    for (int idx = t; idx < DEG*NRBF; idx += 64){
        int e = idx / NRBF, k = idx % NRBF;
        float rs = rS[e];
        rbfL[e][k] = sinf((float)(k+1) * (PI_F/RC) * rs) / rs;
    }
    if (t == 0){
        float s = 0.0f;
        for (int e = 0; e < DEG; e++) s += frL[e];
        float fbn = sqrtf(s);
        invD = (fbn > 0.0f) ? 1.0f/fbn : 1.0f;
    }
    __syncthreads();

    int gcA = SS + t, gcB = SS + 64 + t;       // m2
    int gcC = 2*SS + t, gcD = 2*SS + 64 + t;   // m3
    float fwA[NRBF], fwB[NRBF], fwC[NRBF], fwD[NRBF];
    #pragma unroll
    for (int k = 0; k < NRBF; k++){
        fwA[k] = filt_w[k*(3*SS) + gcA];
        fwB[k] = filt_w[k*(3*SS) + gcB];
        fwC[k] = filt_w[k*(3*SS) + gcC];
        fwD[k] = filt_w[k*(3*SS) + gcD];
    }
    float fbA = filt_b[gcA], fbB = filt_b[gcB];
    float fbC = filt_b[gcC], fbD = filt_b[gcD];
    float phA = phiW[gcA], phB = phiW[gcB];
    float phC = phiW[gcC], phD = phiW[gcD];
    float iD  = invD;
    int   s3C = t % 3;
    int   s3D = (t + 64) % 3;

    float accA = 0.f, accB = 0.f, accC = 0.f, accD = 0.f;
    for (int e = 0; e < DEG; e++){
        float mc = mcL[e];
        if (mc == 0.0f) continue;   // wave-uniform
        const float4* rv = (const float4*)(&rbfL[e][0]);
        float4 r0 = rv[0], r1 = rv[1], r2 = rv[2], r3 = rv[3], r4 = rv[4];
        float rr[20] = {r0.x,r0.y,r0.z,r0.w, r1.x,r1.y,r1.z,r1.w,
                        r2.x,r2.y,r2.z,r2.w, r3.x,r3.y,r3.z,r3.w,
                        r4.x,r4.y,r4.z,r4.w};
        float wA = fbA, wB = fbB, wC = fbC, wD = fbD;
        #pragma unroll
        for (int k = 0; k < NRBF; k++){
            wA = fmaf(rr[k], fwA[k], wA);
            wB = fmaf(rr[k], fwB[k], wB);
            wC = fmaf(rr[k], fwC[k], wC);
            wD = fmaf(rr[k], fwD[k], wD);
        }
        accA = fmaf(phA*mc, wA, accA);
        accB = fmaf(phB*mc, wB, accB);
        accC = fmaf(phC*mc*eV[e][s3C]*iD, wC, accC);
        accD = fmaf(phD*mc*eV[e][s3D]*iD, wD, accD);
    }
    int nf = node_from[n*DEG];
    state[nf*SS + t]      = accA;
    state[nf*SS + 64 + t] = accB;
    sv[nf*SS + t]         = accC;
    sv[nf*SS + 64 + t]    = accD;
}

// ---------------------------------------------------------------------------
// Kernel 3: per-node update as a blocked GEMM. 625 blocks x 128 threads,
// NBK=16 nodes/block. Thread tile = 4 nodes x 4 channels:
//   cg = t&31 -> channels c0=4cg..+3 ; ng = t>>5 -> nodes n0=4ng..+3.
// x operands live in LDS transposed [k][node] (row stride PAD=20 floats,
// 16B-aligned rows): one ds_read_b128 per k feeds 32 FMAs.
// Weights stream from L2 as coalesced float4 (512B/wave, lane-dedup'd).
// ---------------------------------------------------------------------------
__global__ __launch_bounds__(128) void k_update(
    const float* __restrict__ state, const float* __restrict__ sv,
    const float* __restrict__ u_w, const float* __restrict__ v_w,
    const float* __restrict__ upd_w1, const float* __restrict__ upd_b1,
    const float* __restrict__ upd_w2, const float* __restrict__ upd_b2,
    const int* __restrict__ ngi, float* __restrict__ gs){
    __shared__ float svT[SS*PAD];      // sv transposed  [k][node]
    __shared__ float xT[2*SS*PAD];     // rows 0..127 Vnorm, 128..255 state
    __shared__ float hT[SS*PAD];       // h transposed
    __shared__ float dL[NBK];
    __shared__ int   gIdx[NBK];
    int t  = threadIdx.x;
    int cg = t & 31, ng = t >> 5;
    int c0 = 4*cg,  n0 = 4*ng;
    int nb = blockIdx.x * NBK;

    if (t < NBK) gIdx[t] = ngi[nb + t];

    // ---- stage sv, state transposed: thread (sg=t&31, ig=t>>5) loads a
    // 4x4 tile (nodes 4ig.., s 4sg..) and writes it transposed.
    {
        int sg = cg, ig = ng;
        int s0 = 4*sg;
        float4 a0 = *(const float4*)(sv + (nb + 4*ig + 0)*SS + s0);
        float4 a1 = *(const float4*)(sv + (nb + 4*ig + 1)*SS + s0);
        float4 a2 = *(const float4*)(sv + (nb + 4*ig + 2)*SS + s0);
        float4 a3 = *(const float4*)(sv + (nb + 4*ig + 3)*SS + s0);
        *(float4*)(svT + (s0+0)*PAD + 4*ig) = make_float4(a0.x,a1.x,a2.x,a3.x);
        *(float4*)(svT + (s0+1)*PAD + 4*ig) = make_float4(a0.y,a1.y,a2.y,a3.y);
        *(float4*)(svT + (s0+2)*PAD + 4*ig) = make_float4(a0.z,a1.z,a2.z,a3.z);
        *(float4*)(svT + (s0+3)*PAD + 4*ig) = make_float4(a0.w,a1.w,a2.w,a3.w);
        float4 b0 = *(const float4*)(state + (nb + 4*ig + 0)*SS + s0);
        float4 b1 = *(const float4*)(state + (nb + 4*ig + 1)*SS + s0);
        float4 b2 = *(const float4*)(state + (nb + 4*ig + 2)*SS + s0);
        float4 b3 = *(const float4*)(state + (nb + 4*ig + 3)*SS + s0);
        *(float4*)(xT + (SS+s0+0)*PAD + 4*ig) = make_float4(b0.x,b1.x,b2.x,b3.x);
        *(float4*)(xT + (SS+s0+1)*PAD + 4*ig) = make_float4(b0.y,b1.y,b2.y,b3.y);
        *(float4*)(xT + (SS+s0+2)*PAD + 4*ig) = make_float4(b0.z,b1.z,b2.z,b3.z);
        *(float4*)(xT + (SS+s0+3)*PAD + 4*ig) = make_float4(b0.w,b1.w,b2.w,b3.w);
    }
    __syncthreads();

    // ---- Phase A: U,V (4n x 4c per thread)
    float accU[4][4], accV[4][4];     // [j: channel][i: node]
    #pragma unroll
    for (int j = 0; j < 4; j++)
        #pragma unroll
        for (int i = 0; i < 4; i++){ accU[j][i]=0.f; accV[j][i]=0.f; }
    #pragma unroll 2
    for (int k = 0; k < SS; k++){
        float4 xv = *(const float4*)(svT + k*PAD + n0);
        float4 wu = *(const float4*)(u_w + k*SS + c0);
        float4 wv = *(const float4*)(v_w + k*SS + c0);
        float xa[4] = {xv.x, xv.y, xv.z, xv.w};
        float wua[4] = {wu.x, wu.y, wu.z, wu.w};
        float wva[4] = {wv.x, wv.y, wv.z, wv.w};
        #pragma unroll
        for (int j = 0; j < 4; j++)
            #pragma unroll
            for (int i = 0; i < 4; i++){
                accU[j][i] = fmaf(xa[i], wua[j], accU[j][i]);
                accV[j][i] = fmaf(xa[i], wva[j], accV[j][i]);
            }
    }

    // d[n] = sum_c U*V : reduce over 32 channel-groups (lanes within 32)
    float pd[4];
    #pragma unroll
    for (int i = 0; i < 4; i++){
        pd[i] = accU[0][i]*accV[0][i] + accU[1][i]*accV[1][i]
              + accU[2][i]*accV[2][i] + accU[3][i]*accV[3][i];
    }
    #pragma unroll
    for (int mask = 1; mask <= 16; mask <<= 1){
        #pragma unroll
        for (int i = 0; i < 4; i++) pd[i] += __shfl_xor(pd[i], mask);
    }
    if (cg == 0){
        #pragma unroll
        for (int i = 0; i < 4; i++) dL[n0+i] = pd[i];
    }

    // Vnorm rows: xT[c][n] = sqrt(3)*|V|
    const float SQ3 = 1.7320508075688772f;
    #pragma unroll
    for (int j = 0; j < 4; j++)
        *(float4*)(xT + (c0+j)*PAD + n0) =
            make_float4(SQ3*fabsf(accV[j][0]), SQ3*fabsf(accV[j][1]),
                        SQ3*fabsf(accV[j][2]), SQ3*fabsf(accV[j][3]));
    __syncthreads();

    float dreg[4];
    #pragma unroll
    for (int i = 0; i < 4; i++) dreg[i] = dL[n0+i];

    // ---- Phase B: h = silu([Vnorm,state] @ upd_w1 + b1)
    float accH[4][4];
    #pragma unroll
    for (int j = 0; j < 4; j++)
        #pragma unroll
        for (int i = 0; i < 4; i++) accH[j][i] = 0.f;
    #pragma unroll 2
    for (int k = 0; k < 2*SS; k++){
        float4 xv = *(const float4*)(xT + k*PAD + n0);
        float4 ww = *(const float4*)(upd_w1 + k*SS + c0);
        float xa[4] = {xv.x, xv.y, xv.z, xv.w};
        float wa[4] = {ww.x, ww.y, ww.z, ww.w};
        #pragma unroll
        for (int j = 0; j < 4; j++)
            #pragma unroll
            for (int i = 0; i < 4; i++)
                accH[j][i] = fmaf(xa[i], wa[j], accH[j][i]);
    }
    {
        float4 b1v = *(const float4*)(upd_b1 + c0);
        float ba[4] = {b1v.x, b1v.y, b1v.z, b1v.w};
        #pragma unroll
        for (int j = 0; j < 4; j++)
            *(float4*)(hT + (c0+j)*PAD + n0) =
                make_float4(silu_f(accH[j][0]+ba[j]), silu_f(accH[j][1]+ba[j]),
                            silu_f(accH[j][2]+ba[j]), silu_f(accH[j][3]+ba[j]));
    }
    __syncthreads();

    // ---- Phase C: a_sv (cols S..2S), a_ss (cols 2S..3S)
    float a2[4][4], a3[4][4];
    #pragma unroll
    for (int j = 0; j < 4; j++)
        #pragma unroll
        for (int i = 0; i < 4; i++){ a2[j][i]=0.f; a3[j][i]=0.f; }
    #pragma unroll 2
    for (int k = 0; k < SS; k++){
        float4 hx = *(const float4*)(hT + k*PAD + n0);
        float4 w2 = *(const float4*)(upd_w2 + k*3*SS + SS   + c0);
        float4 w3 = *(const float4*)(upd_w2 + k*3*SS + 2*SS + c0);
        float ha[4] = {hx.x, hx.y, hx.z, hx.w};
        float w2a[4] = {w2.x, w2.y, w2.z, w2.w};
        float w3a[4] = {w3.x, w3.y, w3.z, w3.w};
        #pragma unroll
        for (int j = 0; j < 4; j++)
            #pragma unroll
            for (int i = 0; i < 4; i++){
                a2[j][i] = fmaf(ha[i], w2a[j], a2[j][i]);
                a3[j][i] = fmaf(ha[i], w3a[j], a3[j][i]);
            }
    }
    float4 bsv4 = *(const float4*)(upd_b2 + SS   + c0);
    float4 bss4 = *(const float4*)(upd_b2 + 2*SS + c0);
    float bsv[4] = {bsv4.x, bsv4.y, bsv4.z, bsv4.w};
    float bss[4] = {bss4.x, bss4.y, bss4.z, bss4.w};
    #pragma unroll
    for (int i = 0; i < 4; i++){
        int g = gIdx[n0+i];
        float d3 = 3.0f * dreg[i];
        #pragma unroll
        for (int j = 0; j < 4; j++){
            float ns = (a3[j][i] + bss[j]) + d3*(a2[j][i] + bsv[j]);
            atomicAdd(&gs[g*SS + c0 + j], ns);
        }
    }
}

// ---------------------------------------------------------------------------
// Kernel 4: readout per graph
// ---------------------------------------------------------------------------
__global__ __launch_bounds__(128) void k_out(
    const float* __restrict__ gs,
    const float* __restrict__ w1, const float* __restrict__ b1,
    const float* __restrict__ w2, const float* __restrict__ b2,
    float* __restrict__ out){
    __shared__ float gsL[SS];
    __shared__ float red[2];
    int g = blockIdx.x, t = threadIdx.x;
    gsL[t] = gs[g*SS + t];
    __syncthreads();
    float acc = b1[t];
    #pragma unroll 4
    for (int s = 0; s < SS; s++) acc = fmaf(gsL[s], w1[s*SS + t], acc);
    float p = silu_f(acc) * w2[t];
    for (int off = 32; off; off >>= 1) p += __shfl_down(p, off);
    if ((t & 63) == 0) red[t >> 6] = p;
    __syncthreads();
    if (t == 0) out[g] = red[0] + red[1] + b2[0];
}

extern "C" void kernel_launch(void* const* d_in, const int* in_sizes, int n_in,
                              void* d_out, int out_size, void* d_ws, size_t ws_size,
                              hipStream_t stream) {
    const float* evd     = (const float*)d_in[0];
    const float* elen    = (const float*)d_in[1];
    const int*   nfrom   = (const int*)  d_in[2];
    const int*   ngi     = (const int*)  d_in[3];
    const float* emb0    = (const float*)d_in[5];
    const float* phi_w1  = (const float*)d_in[6];
    const float* phi_b1  = (const float*)d_in[7];
    const float* phi_w2  = (const float*)d_in[8];
    const float* phi_b2  = (const float*)d_in[9];
    const float* filt_w  = (const float*)d_in[10];
    const float* filt_b  = (const float*)d_in[11];
    const float* u_w     = (const float*)d_in[12];
    const float* v_w     = (const float*)d_in[13];
    const float* upd_w1  = (const float*)d_in[14];
    const float* upd_b1  = (const float*)d_in[15];
    const float* upd_w2  = (const float*)d_in[16];
    const float* upd_b2  = (const float*)d_in[17];
    const float* out_w1  = (const float*)d_in[18];
    const float* out_b1  = (const float*)d_in[19];
    const float* out_w2  = (const float*)d_in[20];
    const float* out_b2  = (const float*)d_in[21];

    float* ws    = (float*)d_ws;
    float* phiW  = ws;                       // 384 (pad to 512)
    float* state = ws + 512;                 // N*S
    float* sv    = state + NN*SS;            // N*S
    float* gs    = sv + NN*SS;               // G*S

    k_phi<<<12, 128, 0, stream>>>(emb0, phi_w1, phi_b1, phi_w2, phi_b2, phiW, gs);
    k_edge<<<NN, 64, 0, stream>>>(evd, elen, nfrom, filt_w, filt_b, phiW, state, sv);
    k_update<<<NN/NBK, 128, 0, stream>>>(state, sv, u_w, v_w,
                                         upd_w1, upd_b1, upd_w2, upd_b2, ngi, gs);
    k_out<<<GG, 128, 0, stream>>>(gs, out_w1, out_b1, out_w2, out_b2, (float*)d_out);
}

// Round 6
// 201.000 us; speedup vs baseline: 1.2144x; 1.2144x over previous
//
#include <hip/hip_runtime.h>
#include <math.h>

#define NN   10000
#define DEG  16
#define SS   128
#define NRBF 20
#define GG   64
#define RC   10.0f
#define PI_F 3.14159265358979323846f
#define NBK  8           // nodes per fused block
#define PADN 10          // LDS row stride in floats (8 nodes + 2 pad)

__device__ __forceinline__ float silu_f(float x){
    return x / (1.0f + __expf(-x));
}

// ---------------------------------------------------------------------------
// Kernel 1: phi (uniform across edges at round 0) — fused h + phiW slice.
// 12 blocks; each redundantly computes h, then 32 phiW channels. Zeroes gs.
// ---------------------------------------------------------------------------
__global__ __launch_bounds__(128) void k_phi(
    const float* __restrict__ emb0,
    const float* __restrict__ w1, const float* __restrict__ b1,
    const float* __restrict__ w2, const float* __restrict__ b2,
    float* __restrict__ phiW, float* __restrict__ gs){
    __shared__ float s0[SS];
    __shared__ float hL[SS];
    __shared__ float part[4][32];
    int t = threadIdx.x;
    for (int i = blockIdx.x*128 + t; i < GG*SS; i += 12*128) gs[i] = 0.0f;
    s0[t] = 128.0f * emb0[t];
    __syncthreads();
    float acc = b1[t];
    #pragma unroll 4
    for (int s = 0; s < SS; s++) acc = fmaf(s0[s], w1[s*SS + t], acc);
    hL[t] = silu_f(acc);
    __syncthreads();
    int c  = blockIdx.x*32 + (t & 31);
    int kk = t >> 5;
    float a = 0.0f;
    int sbase = kk * 32;
    #pragma unroll 8
    for (int s = 0; s < 32; s++)
        a = fmaf(hL[sbase + s], w2[(sbase + s)*3*SS + c], a);
    part[kk][t & 31] = a;
    __syncthreads();
    if (t < 32){
        int cc = blockIdx.x*32 + t;
        phiW[cc] = b2[cc] + part[0][t] + part[1][t] + part[2][t] + part[3][t];
    }
}

// ---------------------------------------------------------------------------
// Kernel 2 (FUSED): per 8-node block: edge phase -> state/sv in LDS
// (transposed [k][node]) -> update phase -> atomic graph accumulate.
// 128 threads. Edge phase: wave wv covers nodes 4wv..4wv+3, lane l covers
// channels {S+l, S+64+l, 2S+l, 2S+64+l} with filt_w columns in registers.
// Update phase: thread tile = 2 nodes x 4 channels; LDS x-reads are b64.
// ---------------------------------------------------------------------------
__global__ __launch_bounds__(128) void k_fused(
    const float* __restrict__ evd, const float* __restrict__ elen,
    const int* __restrict__ ngi,
    const float* __restrict__ filt_w, const float* __restrict__ filt_b,
    const float* __restrict__ phiW,
    const float* __restrict__ u_w, const float* __restrict__ v_w,
    const float* __restrict__ upd_w1, const float* __restrict__ upd_b1,
    const float* __restrict__ upd_w2, const float* __restrict__ upd_b2,
    float* __restrict__ gs){
    __shared__ float  rbfL[NBK*DEG*NRBF];   // [edge 128][k 20]
    __shared__ float4 edgeS[NBK*DEG];       // {mc, sx, sy, sz} (s = eV*mc*invD)
    __shared__ float  frS[NBK*DEG];
    __shared__ float  svT[SS*PADN];         // sv [k][node]; reused for h
    __shared__ float  xT[2*SS*PADN];        // rows 0..127 Vnorm, 128..255 state
    __shared__ float  invD[NBK];
    __shared__ float  dL[NBK];
    __shared__ int    gIdx[NBK];

    int t  = threadIdx.x;
    int nb = blockIdx.x * NBK;

    // ---- edge prologue: thread t owns local edge t
    {
        int e = nb*DEG + t;
        float x = evd[3*e+0], y = evd[3*e+1], z = evd[3*e+2];
        float r = sqrtf(x*x + y*y + z*z);
        float len  = elen[e];
        float mask = (fabsf(len) <= RC) ? 1.0f : 0.0f;
        float cut  = (r < RC) ? 0.5f*(__cosf(PI_F*(1.0f/RC)*r) + 1.0f) : 0.0f;
        float mc   = mask * cut;
        float rs   = fmaxf(r, 1e-12f);
        frS[t]   = mask * r * r;
        edgeS[t] = make_float4(mc, x, y, z);
        float inv_rs = 1.0f / rs;
        float base   = (PI_F/RC) * rs;
        float rb[NRBF];
        #pragma unroll
        for (int k = 0; k < NRBF; k++)
            rb[k] = __sinf(base * (float)(k+1)) * inv_rs;
        float4* dst = (float4*)(rbfL + t*NRBF);
        dst[0] = make_float4(rb[0],rb[1],rb[2],rb[3]);
        dst[1] = make_float4(rb[4],rb[5],rb[6],rb[7]);
        dst[2] = make_float4(rb[8],rb[9],rb[10],rb[11]);
        dst[3] = make_float4(rb[12],rb[13],rb[14],rb[15]);
        dst[4] = make_float4(rb[16],rb[17],rb[18],rb[19]);
    }
    __syncthreads();
    if (t < NBK){
        float s = 0.0f;
        #pragma unroll
        for (int e = 0; e < DEG; e++) s += frS[t*DEG + e];
        float fb = sqrtf(s);
        invD[t] = (fb > 0.0f) ? 1.0f/fb : 1.0f;
        gIdx[t] = ngi[nb + t];
    }
    __syncthreads();
    {   // fold mc*invD into the eV components
        float4 es = edgeS[t];
        float f = es.x * invD[t >> 4];
        edgeS[t] = make_float4(es.x, es.y*f, es.z*f, es.w*f);
    }
    __syncthreads();

    // ---- edge main loop
    {
        int wv = t >> 6, l = t & 63;
        int gcA = SS + l, gcB = SS + 64 + l;
        int gcC = 2*SS + l, gcD = 2*SS + 64 + l;
        float fwA[NRBF], fwB[NRBF], fwC[NRBF], fwD[NRBF];
        #pragma unroll
        for (int k = 0; k < NRBF; k++){
            fwA[k] = filt_w[k*(3*SS) + gcA];
            fwB[k] = filt_w[k*(3*SS) + gcB];
            fwC[k] = filt_w[k*(3*SS) + gcC];
            fwD[k] = filt_w[k*(3*SS) + gcD];
        }
        float fbA = filt_b[gcA], fbB = filt_b[gcB];
        float fbC = filt_b[gcC], fbD = filt_b[gcD];
        float phA = phiW[gcA], phB = phiW[gcB];
        float phC = phiW[gcC], phD = phiW[gcD];
        int s3C = l % 3, s3D = (l + 64) % 3;

        for (int ni = 0; ni < 4; ni++){
            int node = 4*wv + ni;
            float accA = 0.f, accB = 0.f, accC = 0.f, accD = 0.f;
            #pragma unroll 4
            for (int e = 0; e < DEG; e++){
                int eg = node*DEG + e;
                const float4* rv = (const float4*)(rbfL + eg*NRBF);
                float4 r0 = rv[0], r1 = rv[1], r2 = rv[2], r3 = rv[3], r4 = rv[4];
                float rr[NRBF] = {r0.x,r0.y,r0.z,r0.w, r1.x,r1.y,r1.z,r1.w,
                                  r2.x,r2.y,r2.z,r2.w, r3.x,r3.y,r3.z,r3.w,
                                  r4.x,r4.y,r4.z,r4.w};
                float4 es = edgeS[eg];
                float wA = fbA, wB = fbB, wC = fbC, wD = fbD;
                #pragma unroll
                for (int k = 0; k < NRBF; k++){
                    wA = fmaf(rr[k], fwA[k], wA);
                    wB = fmaf(rr[k], fwB[k], wB);
                    wC = fmaf(rr[k], fwC[k], wC);
                    wD = fmaf(rr[k], fwD[k], wD);
                }
                float fC = (s3C == 0) ? es.y : ((s3C == 1) ? es.z : es.w);
                float fD = (s3D == 0) ? es.y : ((s3D == 1) ? es.z : es.w);
                accA = fmaf(phA*es.x, wA, accA);
                accB = fmaf(phB*es.x, wB, accB);
                accC = fmaf(phC*fC,  wC, accC);
                accD = fmaf(phD*fD,  wD, accD);
            }
            xT[(SS + l)*PADN + node]      = accA;   // state ch l
            xT[(SS + 64 + l)*PADN + node] = accB;   // state ch 64+l
            svT[l*PADN + node]            = accC;   // sv ch l
            svT[(64 + l)*PADN + node]     = accD;   // sv ch 64+l
        }
    }
    __syncthreads();

    // ---- update phase: thread tile 2 nodes (n0, n0+1) x 4 channels (c0..)
    int cg = t & 31, ng = t >> 5;
    int c0 = 4*cg, n0 = 2*ng;

    // Phase A: U = sv@u_w, V = sv@v_w
    float accU[4][2], accV[4][2];
    #pragma unroll
    for (int j = 0; j < 4; j++){
        accU[j][0] = accU[j][1] = 0.f;
        accV[j][0] = accV[j][1] = 0.f;
    }
    #pragma unroll 4
    for (int k = 0; k < SS; k++){
        float2 xv = *(const float2*)(svT + k*PADN + n0);
        float4 wu = *(const float4*)(u_w + k*SS + c0);
        float4 wv4 = *(const float4*)(v_w + k*SS + c0);
        float wua[4] = {wu.x, wu.y, wu.z, wu.w};
        float wva[4] = {wv4.x, wv4.y, wv4.z, wv4.w};
        #pragma unroll
        for (int j = 0; j < 4; j++){
            accU[j][0] = fmaf(xv.x, wua[j], accU[j][0]);
            accU[j][1] = fmaf(xv.y, wua[j], accU[j][1]);
            accV[j][0] = fmaf(xv.x, wva[j], accV[j][0]);
            accV[j][1] = fmaf(xv.y, wva[j], accV[j][1]);
        }
    }
    // d[n] = sum_c U*V (reduce across the 32 channel-groups)
    float pd0 = 0.f, pd1 = 0.f;
    #pragma unroll
    for (int j = 0; j < 4; j++){
        pd0 = fmaf(accU[j][0], accV[j][0], pd0);
        pd1 = fmaf(accU[j][1], accV[j][1], pd1);
    }
    #pragma unroll
    for (int m = 1; m <= 16; m <<= 1){
        pd0 += __shfl_xor(pd0, m);
        pd1 += __shfl_xor(pd1, m);
    }
    if (cg == 0){ dL[n0] = pd0; dL[n0+1] = pd1; }
    // Vnorm = sqrt(3)*|V| into xT rows 0..127
    const float SQ3 = 1.7320508075688772f;
    #pragma unroll
    for (int j = 0; j < 4; j++){
        xT[(c0+j)*PADN + n0]     = SQ3 * fabsf(accV[j][0]);
        xT[(c0+j)*PADN + n0 + 1] = SQ3 * fabsf(accV[j][1]);
    }
    __syncthreads();
    float d30 = 3.0f*dL[n0], d31 = 3.0f*dL[n0+1];

    // Phase B: h = silu([Vnorm,state] @ upd_w1 + b1)  -> svT reused as h
    float accH[4][2];
    #pragma unroll
    for (int j = 0; j < 4; j++) accH[j][0] = accH[j][1] = 0.f;
    #pragma unroll 4
    for (int k = 0; k < 2*SS; k++){
        float2 xv = *(const float2*)(xT + k*PADN + n0);
        float4 w4 = *(const float4*)(upd_w1 + k*SS + c0);
        float wa[4] = {w4.x, w4.y, w4.z, w4.w};
        #pragma unroll
        for (int j = 0; j < 4; j++){
            accH[j][0] = fmaf(xv.x, wa[j], accH[j][0]);
            accH[j][1] = fmaf(xv.y, wa[j], accH[j][1]);
        }
    }
    {
        float4 b1v = *(const float4*)(upd_b1 + c0);
        float ba[4] = {b1v.x, b1v.y, b1v.z, b1v.w};
        #pragma unroll
        for (int j = 0; j < 4; j++){
            svT[(c0+j)*PADN + n0]     = silu_f(accH[j][0] + ba[j]);
            svT[(c0+j)*PADN + n0 + 1] = silu_f(accH[j][1] + ba[j]);
        }
    }
    __syncthreads();

    // Phase C: a_sv (w2 cols S..2S), a_ss (cols 2S..3S)
    float a2[4][2], a3[4][2];
    #pragma unroll
    for (int j = 0; j < 4; j++){
        a2[j][0] = a2[j][1] = 0.f;
        a3[j][0] = a3[j][1] = 0.f;
    }
    #pragma unroll 4
    for (int k = 0; k < SS; k++){
        float2 hx = *(const float2*)(svT + k*PADN + n0);
        float4 w2 = *(const float4*)(upd_w2 + k*3*SS + SS   + c0);
        float4 w3 = *(const float4*)(upd_w2 + k*3*SS + 2*SS + c0);
        float w2a[4] = {w2.x, w2.y, w2.z, w2.w};
        float w3a[4] = {w3.x, w3.y, w3.z, w3.w};
        #pragma unroll
        for (int j = 0; j < 4; j++){
            a2[j][0] = fmaf(hx.x, w2a[j], a2[j][0]);
            a2[j][1] = fmaf(hx.y, w2a[j], a2[j][1]);
            a3[j][0] = fmaf(hx.x, w3a[j], a3[j][0]);
            a3[j][1] = fmaf(hx.y, w3a[j], a3[j][1]);
        }
    }
    float4 bsv4 = *(const float4*)(upd_b2 + SS   + c0);
    float4 bss4 = *(const float4*)(upd_b2 + 2*SS + c0);
    float bsv[4] = {bsv4.x, bsv4.y, bsv4.z, bsv4.w};
    float bss[4] = {bss4.x, bss4.y, bss4.z, bss4.w};
    int g0 = gIdx[n0], g1 = gIdx[n0+1];
    #pragma unroll
    for (int j = 0; j < 4; j++){
        float ns0 = (a3[j][0] + bss[j]) + d30*(a2[j][0] + bsv[j]);
        float ns1 = (a3[j][1] + bss[j]) + d31*(a2[j][1] + bsv[j]);
        atomicAdd(&gs[g0*SS + c0 + j], ns0);
        atomicAdd(&gs[g1*SS + c0 + j], ns1);
    }
}

// ---------------------------------------------------------------------------
// Kernel 3: readout per graph
// ---------------------------------------------------------------------------
__global__ __launch_bounds__(128) void k_out(
    const float* __restrict__ gs,
    const float* __restrict__ w1, const float* __restrict__ b1,
    const float* __restrict__ w2, const float* __restrict__ b2,
    float* __restrict__ out){
    __shared__ float gsL[SS];
    __shared__ float red[2];
    int g = blockIdx.x, t = threadIdx.x;
    gsL[t] = gs[g*SS + t];
    __syncthreads();
    float acc = b1[t];
    #pragma unroll 4
    for (int s = 0; s < SS; s++) acc = fmaf(gsL[s], w1[s*SS + t], acc);
    float p = silu_f(acc) * w2[t];
    for (int off = 32; off; off >>= 1) p += __shfl_down(p, off);
    if ((t & 63) == 0) red[t >> 6] = p;
    __syncthreads();
    if (t == 0) out[g] = red[0] + red[1] + b2[0];
}

extern "C" void kernel_launch(void* const* d_in, const int* in_sizes, int n_in,
                              void* d_out, int out_size, void* d_ws, size_t ws_size,
                              hipStream_t stream) {
    const float* evd     = (const float*)d_in[0];
    const float* elen    = (const float*)d_in[1];
    const int*   ngi     = (const int*)  d_in[3];
    const float* emb0    = (const float*)d_in[5];
    const float* phi_w1  = (const float*)d_in[6];
    const float* phi_b1  = (const float*)d_in[7];
    const float* phi_w2  = (const float*)d_in[8];
    const float* phi_b2  = (const float*)d_in[9];
    const float* filt_w  = (const float*)d_in[10];
    const float* filt_b  = (const float*)d_in[11];
    const float* u_w     = (const float*)d_in[12];
    const float* v_w     = (const float*)d_in[13];
    const float* upd_w1  = (const float*)d_in[14];
    const float* upd_b1  = (const float*)d_in[15];
    const float* upd_w2  = (const float*)d_in[16];
    const float* upd_b2  = (const float*)d_in[17];
    const float* out_w1  = (const float*)d_in[18];
    const float* out_b1  = (const float*)d_in[19];
    const float* out_w2  = (const float*)d_in[20];
    const float* out_b2  = (const float*)d_in[21];

    float* ws   = (float*)d_ws;
    float* phiW = ws;            // 384 (pad to 512)
    float* gs   = ws + 512;      // G*S

    k_phi<<<12, 128, 0, stream>>>(emb0, phi_w1, phi_b1, phi_w2, phi_b2, phiW, gs);
    k_fused<<<NN/NBK, 128, 0, stream>>>(evd, elen, ngi, filt_w, filt_b, phiW,
                                        u_w, v_w, upd_w1, upd_b1, upd_w2, upd_b2, gs);
    k_out<<<GG, 128, 0, stream>>>(gs, out_w1, out_b1, out_w2, out_b2, (float*)d_out);
}